// Round 1
// baseline (2505.380 us; speedup 1.0000x reference)
//
#include <hip/hip_runtime.h>
#include <hip/hip_bf16.h>

// ---------- constants ----------
#define BN    2048
#define LP    31          // patches per signal
#define GTOT  63488       // BN*LP
#define HH    128

// ---------- helpers ----------
__device__ __forceinline__ unsigned short f2bf(float v) {
    unsigned int b = __float_as_uint(v);
    unsigned int r = (b + 0x7fffu + ((b >> 16) & 1u)) >> 16;   // RNE
    return (unsigned short)r;
}
__device__ __forceinline__ float bf2f(unsigned short u) {
    return __uint_as_float(((unsigned int)u) << 16);
}
__device__ __forceinline__ float bflo(unsigned int w) {
    return __uint_as_float(w << 16);
}
__device__ __forceinline__ float bfhi(unsigned int w) {
    return __uint_as_float(w & 0xffff0000u);
}
__device__ __forceinline__ float sigm(float x) {
    return 1.f / (1.f + __expf(-x));
}
__device__ __forceinline__ float tanh_(float x) {
    return 2.f / (1.f + __expf(-2.f * x)) - 1.f;
}
__device__ __forceinline__ float adjW(int i, int j) {
    const float inv[8] = {1.f/4.f, 1.f/5.f, 1.f/6.f, 1.f/7.f,
                          1.f/7.f, 1.f/6.f, 1.f/5.f, 1.f/4.f};
    int d = i - j; d = d < 0 ? -d : d;
    return (d >= 1 && d <= 4) ? inv[i] : 0.f;
}

// =====================================================================
// K1: fused graph stage: patchify -> sage0 -> LN/relu -> 2x(sage,LN,relu,res)
//     -> node mean -> patch_features (fp32, into d_out region)
// block = 256 thr, 8 graphs (64 rows x 128 feat) per block.
// thread t: graph g = t>>5 (0..7), col set o = (t&31) + 32k, rows = all 8 nodes.
// =====================================================================
__device__ __forceinline__ void mm_acc(float acc[8][4], const float* __restrict__ rows,
                                       const float* __restrict__ wS, int tc)
{
    #pragma unroll 4
    for (int f4 = 0; f4 < 32; ++f4) {
        const int f = f4 << 2;
        float4 a[8];
        #pragma unroll
        for (int i = 0; i < 8; ++i) a[i] = *(const float4*)(rows + i * 128 + f);
        #pragma unroll
        for (int k = 0; k < 4; ++k) {
            const float4 w = *(const float4*)(wS + (tc + 32 * k) * 132 + f);
            #pragma unroll
            for (int i = 0; i < 8; ++i)
                acc[i][k] += a[i].x * w.x + a[i].y * w.y + a[i].z * w.z + a[i].w * w.w;
        }
    }
}

template<bool RES>
__device__ __forceinline__ void ln_relu_store(float acc[8][4], float (*hS)[128],
        int g, int tc, const float* __restrict__ lng, const float* __restrict__ lnb, int lidx)
{
    float gam[4], bet[4];
    #pragma unroll
    for (int k = 0; k < 4; ++k) {
        int o = tc + 32 * k;
        gam[k] = lng[lidx * 128 + o];
        bet[k] = lnb[lidx * 128 + o];
    }
    #pragma unroll
    for (int i = 0; i < 8; ++i) {
        float s  = acc[i][0] + acc[i][1] + acc[i][2] + acc[i][3];
        float s2 = acc[i][0]*acc[i][0] + acc[i][1]*acc[i][1]
                 + acc[i][2]*acc[i][2] + acc[i][3]*acc[i][3];
        #pragma unroll
        for (int m = 1; m < 32; m <<= 1) {
            s  += __shfl_xor(s,  m, 64);
            s2 += __shfl_xor(s2, m, 64);
        }
        const float mu   = s * (1.f / 128.f);
        const float var  = s2 * (1.f / 128.f) - mu * mu;
        const float rstd = rsqrtf(var + 1e-5f);
        const int r = g * 8 + i;
        #pragma unroll
        for (int k = 0; k < 4; ++k) {
            int o = tc + 32 * k;
            float v = (acc[i][k] - mu) * rstd * gam[k] + bet[k];
            v = fmaxf(v, 0.f);
            hS[r][o] = RES ? (hS[r][o] + v) : v;
        }
    }
}

__global__ __launch_bounds__(256) void k1_sage(
    const float* __restrict__ iq,
    const float* __restrict__ Wl0, const float* __restrict__ bl0, const float* __restrict__ Wr0,
    const float* __restrict__ Wl12, const float* __restrict__ bl12, const float* __restrict__ Wr12,
    const float* __restrict__ lng, const float* __restrict__ lnb,
    float* __restrict__ pf)
{
    __shared__ float hS[64][128];      // 32 KB
    __shared__ float aggS[64][128];    // 32 KB
    __shared__ float wS[128 * 132];    // 66 KB (pad 132 -> conflict-spread)
    __shared__ float xS[64][2];
    __shared__ float axS[64][2];

    const int t  = threadIdx.x;
    const int g  = t >> 5;
    const int tc = t & 31;
    const int g0 = blockIdx.x * 8;

    // ---- load patches ----
    if (t < 128) {
        int r = t >> 1, c = t & 1;
        int gid  = g0 + (r >> 3);
        int node = r & 7;
        int b = gid / 31;
        int p = gid - b * 31;
        xS[r][c] = iq[((size_t)b * 2 + c) * 128 + p * 4 + node];
    }
    __syncthreads();
    if (t < 128) {
        int r = t >> 1, c = t & 1;
        int node = r & 7, base = r & ~7;
        float s = 0.f;
        #pragma unroll
        for (int j = 0; j < 8; ++j) s += adjW(node, j) * xS[base + j][c];
        axS[r][c] = s;
    }
    __syncthreads();

    float acc[8][4];

    // ---- layer 0 (K = 2) ----
    {
        float wlx[4], wly[4], wrx[4], wry[4], bb[4];
        #pragma unroll
        for (int k = 0; k < 4; ++k) {
            int o = tc + 32 * k;
            float2 wl = *(const float2*)(Wl0 + o * 2);
            float2 wr = *(const float2*)(Wr0 + o * 2);
            wlx[k] = wl.x; wly[k] = wl.y; wrx[k] = wr.x; wry[k] = wr.y;
            bb[k] = bl0[o];
        }
        #pragma unroll
        for (int i = 0; i < 8; ++i) {
            int r = g * 8 + i;
            float a0 = axS[r][0], a1 = axS[r][1];
            float x0 = xS[r][0],  x1 = xS[r][1];
            #pragma unroll
            for (int k = 0; k < 4; ++k)
                acc[i][k] = bb[k] + a0 * wlx[k] + a1 * wly[k] + x0 * wrx[k] + x1 * wry[k];
        }
        ln_relu_store<false>(acc, hS, g, tc, lng, lnb, 0);
    }

    // ---- layers 1,2 ----
    for (int l = 0; l < 2; ++l) {
        __syncthreads();                       // hS stable
        // agg = blockdiag(A) * h
        #pragma unroll
        for (int k = 0; k < 4; ++k) {
            int o = tc + 32 * k;
            float hv[8];
            #pragma unroll
            for (int j = 0; j < 8; ++j) hv[j] = hS[g * 8 + j][o];
            #pragma unroll
            for (int i = 0; i < 8; ++i) {
                float s = 0.f;
                #pragma unroll
                for (int j = 0; j < 8; ++j) s += adjW(i, j) * hv[j];
                aggS[g * 8 + i][o] = s;
            }
        }
        // stage Wl
        const float* Wl = Wl12 + l * 16384;
        #pragma unroll
        for (int i = 0; i < 16; ++i) {
            int idx4 = t + 256 * i;
            int o = idx4 >> 5, f = (idx4 & 31) << 2;
            *(float4*)(&wS[o * 132 + f]) = *(const float4*)(Wl + idx4 * 4);
        }
        __syncthreads();                       // agg + Wl ready
        #pragma unroll
        for (int i = 0; i < 8; ++i)
            #pragma unroll
            for (int k = 0; k < 4; ++k) acc[i][k] = 0.f;
        mm_acc(acc, &aggS[g * 8][0], wS, tc);
        __syncthreads();                       // done reading Wl
        const float* Wr = Wr12 + l * 16384;
        #pragma unroll
        for (int i = 0; i < 16; ++i) {
            int idx4 = t + 256 * i;
            int o = idx4 >> 5, f = (idx4 & 31) << 2;
            *(float4*)(&wS[o * 132 + f]) = *(const float4*)(Wr + idx4 * 4);
        }
        __syncthreads();                       // Wr ready
        mm_acc(acc, &hS[g * 8][0], wS, tc);
        __syncthreads();                       // all hS reads done -> safe to overwrite
        #pragma unroll
        for (int k = 0; k < 4; ++k) {
            float bb = bl12[l * 128 + tc + 32 * k];
            #pragma unroll
            for (int i = 0; i < 8; ++i) acc[i][k] += bb;
        }
        ln_relu_store<true>(acc, hS, g, tc, lng, lnb, l + 1);
    }
    __syncthreads();

    // ---- node mean -> patch features ----
    {
        int o = tc * 4;
        float s0 = 0.f, s1 = 0.f, s2 = 0.f, s3 = 0.f;
        #pragma unroll
        for (int i = 0; i < 8; ++i) {
            s0 += hS[g * 8 + i][o + 0];
            s1 += hS[g * 8 + i][o + 1];
            s2 += hS[g * 8 + i][o + 2];
            s3 += hS[g * 8 + i][o + 3];
        }
        float4 v = make_float4(s0 * 0.125f, s1 * 0.125f, s2 * 0.125f, s3 * 0.125f);
        *(float4*)(pf + (size_t)(g0 + g) * 128 + o) = v;
    }
}

// =====================================================================
// K2: xg = src(M=63488,128) @ w_ih^T(384,128) + b_ih  -> bf16
// tile 128x128, K=128 full. grid (496, 3), block 256.
// =====================================================================
__global__ __launch_bounds__(256) void k2_xg(
    const float* __restrict__ src, const float* __restrict__ W,
    const float* __restrict__ bias, unsigned short* __restrict__ out)
{
    __shared__ float At[128 * 132];
    __shared__ float Bt[128 * 132];
    const int t  = threadIdx.x;
    const int m0 = blockIdx.x * 128;
    const int n0 = blockIdx.y * 128;

    #pragma unroll
    for (int i = 0; i < 16; ++i) {
        int idx4 = t + 256 * i;
        int r = idx4 >> 5, f = (idx4 & 31) << 2;
        *(float4*)(&At[r * 132 + f]) = *(const float4*)(src + (size_t)(m0 + r) * 128 + f);
        *(float4*)(&Bt[r * 132 + f]) = *(const float4*)(W + (size_t)(n0 + r) * 128 + f);
    }
    __syncthreads();

    const int ty = t >> 4, tx = t & 15;
    float acc[8][8];
    #pragma unroll
    for (int i = 0; i < 8; ++i)
        #pragma unroll
        for (int j = 0; j < 8; ++j) acc[i][j] = 0.f;

    #pragma unroll 4
    for (int f4 = 0; f4 < 32; ++f4) {
        const int f = f4 << 2;
        float4 a[8];
        #pragma unroll
        for (int i = 0; i < 8; ++i) a[i] = *(const float4*)(&At[(ty + 16 * i) * 132 + f]);
        #pragma unroll
        for (int j = 0; j < 8; ++j) {
            const float4 b = *(const float4*)(&Bt[(tx + 16 * j) * 132 + f]);
            #pragma unroll
            for (int i = 0; i < 8; ++i)
                acc[i][j] += a[i].x * b.x + a[i].y * b.y + a[i].z * b.z + a[i].w * b.w;
        }
    }
    #pragma unroll
    for (int j = 0; j < 8; ++j) {
        int n = n0 + tx + 16 * j;
        float bv = bias[n];
        #pragma unroll
        for (int i = 0; i < 8; ++i) {
            int m = m0 + ty + 16 * i;
            out[(size_t)m * 384 + n] = f2bf(acc[i][j] + bv);
        }
    }
}

// =====================================================================
// K3: GRU layer, 31 timesteps in-kernel. 256 blocks x 8 batch rows, 512 thr.
// w_hh staged bf16 in LDS (98 KB). thread: rowpair rp=t>>7 (rows rp, rp+4),
// o = t&127, owns all 3 gates for its (row,o).
// =====================================================================
__global__ __launch_bounds__(512) void k3_gru(
    const unsigned short* __restrict__ xg, const float* __restrict__ whh,
    const float* __restrict__ bhh, float* __restrict__ o1, float* __restrict__ gout)
{
    __shared__ unsigned short wS[384 * 132];   // ~99 KB
    __shared__ float hS[8][128];               // 4 KB

    const int t = threadIdx.x;
    // stage w_hh -> bf16 LDS
    #pragma unroll
    for (int i = 0; i < 24; ++i) {
        int idx4 = t + 512 * i;                // 0..12287
        int j = idx4 >> 5, f = (idx4 & 31) << 2;
        float4 v = *(const float4*)(whh + (size_t)j * 128 + f);
        unsigned int p0 = (unsigned int)f2bf(v.x) | ((unsigned int)f2bf(v.y) << 16);
        unsigned int p1 = (unsigned int)f2bf(v.z) | ((unsigned int)f2bf(v.w) << 16);
        *(unsigned int*)(&wS[j * 132 + f])     = p0;
        *(unsigned int*)(&wS[j * 132 + f + 2]) = p1;
    }
    ((float*)hS)[t] = 0.f;
    ((float*)hS)[t + 512] = 0.f;

    const int rp = t >> 7;          // 0..3
    const int o  = t & 127;
    const int r0 = rp, r1 = rp + 4;
    const int b0 = blockIdx.x * 8;

    float bh[3];
    #pragma unroll
    for (int gg = 0; gg < 3; ++gg) bh[gg] = bhh[gg * 128 + o];

    const size_t xrow0 = (size_t)(b0 + r0) * 31 * 384;
    const size_t xrow1 = (size_t)(b0 + r1) * 31 * 384;
    __syncthreads();

    for (int ts = 0; ts < 31; ++ts) {
        float a0[3] = {0.f, 0.f, 0.f}, a1[3] = {0.f, 0.f, 0.f};
        #pragma unroll 4
        for (int f4 = 0; f4 < 32; ++f4) {
            const int f = f4 << 2;
            const float4 h0 = *(const float4*)(&hS[r0][f]);
            const float4 h1 = *(const float4*)(&hS[r1][f]);
            #pragma unroll
            for (int gg = 0; gg < 3; ++gg) {
                const uint2 w = *(const uint2*)(&wS[(gg * 128 + o) * 132 + f]);
                const float w0 = bflo(w.x), w1 = bfhi(w.x);
                const float w2 = bflo(w.y), w3 = bfhi(w.y);
                a0[gg] += h0.x * w0 + h0.y * w1 + h0.z * w2 + h0.w * w3;
                a1[gg] += h1.x * w0 + h1.y * w1 + h1.z * w2 + h1.w * w3;
            }
        }
        const size_t xb0 = xrow0 + (size_t)ts * 384;
        const size_t xb1 = xrow1 + (size_t)ts * 384;
        float hnew0, hnew1;
        {
            float xr = bf2f(xg[xb0 + o]), xz = bf2f(xg[xb0 + 128 + o]), xn = bf2f(xg[xb0 + 256 + o]);
            float r = sigm(xr + a0[0] + bh[0]);
            float z = sigm(xz + a0[1] + bh[1]);
            float nn = tanh_(xn + r * (a0[2] + bh[2]));
            float hp = hS[r0][o];
            hnew0 = (1.f - z) * nn + z * hp;
        }
        {
            float xr = bf2f(xg[xb1 + o]), xz = bf2f(xg[xb1 + 128 + o]), xn = bf2f(xg[xb1 + 256 + o]);
            float r = sigm(xr + a1[0] + bh[0]);
            float z = sigm(xz + a1[1] + bh[1]);
            float nn = tanh_(xn + r * (a1[2] + bh[2]));
            float hp = hS[r1][o];
            hnew1 = (1.f - z) * nn + z * hp;
        }
        __syncthreads();               // all matmul reads of hS done
        hS[r0][o] = hnew0;
        hS[r1][o] = hnew1;
        if (o1 != nullptr) {
            o1[((size_t)(b0 + r0) * 31 + ts) * 128 + o] = hnew0;
            o1[((size_t)(b0 + r1) * 31 + ts) * 128 + o] = hnew1;
        }
        if (gout != nullptr && ts == 30) {
            gout[(size_t)(b0 + r0) * 128 + o] = hnew0;
            gout[(size_t)(b0 + r1) * 128 + o] = hnew1;
        }
        __syncthreads();               // writes visible before next step
    }
}

// =====================================================================
// K4: logits = g(2048,128) @ etf(128,8)
// =====================================================================
__global__ __launch_bounds__(256) void k4_logits(
    const float* __restrict__ g, const float* __restrict__ etf, float* __restrict__ logits)
{
    const int idx = blockIdx.x * 256 + threadIdx.x;   // = b*8 + c
    const int b = idx >> 3, c = idx & 7;
    float s = 0.f;
    #pragma unroll 8
    for (int f = 0; f < 128; ++f) s += g[(size_t)b * 128 + f] * etf[f * 8 + c];
    logits[idx] = s;
}

// =====================================================================
extern "C" void kernel_launch(void* const* d_in, const int* in_sizes, int n_in,
                              void* d_out, int out_size, void* d_ws, size_t ws_size,
                              hipStream_t stream) {
    const float* iq   = (const float*)d_in[0];
    const float* Wl0  = (const float*)d_in[1];
    const float* bl0  = (const float*)d_in[2];
    const float* Wr0  = (const float*)d_in[3];
    const float* Wl12 = (const float*)d_in[4];
    const float* bl12 = (const float*)d_in[5];
    const float* Wr12 = (const float*)d_in[6];
    const float* lng  = (const float*)d_in[7];
    const float* lnb  = (const float*)d_in[8];
    const float* wih  = (const float*)d_in[9];
    const float* whh  = (const float*)d_in[10];
    const float* bih  = (const float*)d_in[11];
    const float* bhh  = (const float*)d_in[12];
    const float* etf  = (const float*)d_in[13];

    float* out    = (float*)d_out;
    float* logits = out;                       // 2048*8
    float* gbuf   = out + 16384;               // 2048*128
    float* pf     = out + 16384 + 262144;      // 63488*128

    // ws: xg bf16 (63488*384 = 24379392 ushorts = 48758784 B), then o1 fp32 (32505856 B)
    unsigned short* xg = (unsigned short*)d_ws;
    float* o1 = (float*)((char*)d_ws + 48758784);

    // 1) fused graph stage -> patch_features
    k1_sage<<<7936, 256, 0, stream>>>(iq, Wl0, bl0, Wr0, Wl12, bl12, Wr12, lng, lnb, pf);
    // 2) GRU layer 1
    k2_xg<<<dim3(496, 3), 256, 0, stream>>>(pf, wih, bih, xg);
    k3_gru<<<256, 512, 0, stream>>>(xg, whh, bhh, o1, nullptr);
    // 3) GRU layer 2
    k2_xg<<<dim3(496, 3), 256, 0, stream>>>(o1, wih + 49152, bih + 384, xg);
    k3_gru<<<256, 512, 0, stream>>>(xg, whh + 49152, bhh + 384, nullptr, gbuf);
    // 4) logits
    k4_logits<<<64, 256, 0, stream>>>(gbuf, etf, logits);
}

// Round 2
// 1101.161 us; speedup vs baseline: 2.2752x; 2.2752x over previous
//
#include <hip/hip_runtime.h>
#include <hip/hip_bf16.h>

typedef __attribute__((ext_vector_type(8))) short bf16x8;
typedef __attribute__((ext_vector_type(4))) float f32x4;

// ---------- helpers ----------
__device__ __forceinline__ unsigned short f2bf(float v) {
    unsigned int b = __float_as_uint(v);
    unsigned int r = (b + 0x7fffu + ((b >> 16) & 1u)) >> 16;   // RNE
    return (unsigned short)r;
}
__device__ __forceinline__ float bf2f(unsigned short u) {
    return __uint_as_float(((unsigned int)u) << 16);
}
__device__ __forceinline__ float bflo(unsigned int w) {
    return __uint_as_float(w << 16);
}
__device__ __forceinline__ float bfhi(unsigned int w) {
    return __uint_as_float(w & 0xffff0000u);
}
__device__ __forceinline__ float sigm(float x) {
    return 1.f / (1.f + __expf(-x));
}
__device__ __forceinline__ float tanh_(float x) {
    return 2.f / (1.f + __expf(-2.f * x)) - 1.f;
}
__device__ __forceinline__ float adjW(int i, int j) {
    const float inv[8] = {1.f/4.f, 1.f/5.f, 1.f/6.f, 1.f/7.f,
                          1.f/7.f, 1.f/6.f, 1.f/5.f, 1.f/4.f};
    int d = i - j; d = d < 0 ? -d : d;
    return (d >= 1 && d <= 4) ? inv[i] : 0.f;
}

// =====================================================================
// K0: convert Wl12/Wr12 to bf16 into ws (overwritten later by xg; rewritten
// every replay -> graph-safe).  layout: [wl: 2*128*128][wr: 2*128*128]
// =====================================================================
__global__ __launch_bounds__(256) void k0_wconv(const float* __restrict__ Wl12,
    const float* __restrict__ Wr12, unsigned short* __restrict__ wbf)
{
    int i = blockIdx.x * 256 + threadIdx.x;   // 0..65535
    float v = (i < 32768) ? Wl12[i] : Wr12[i - 32768];
    wbf[i] = f2bf(v);
}

// =====================================================================
// K1: fused graph stage with MFMA.
// block = 512 thr (8 waves, 4 row-groups x 2 col-groups), 16 graphs = 128 rows.
// hS/aggS bf16 in LDS; weights bf16 from L2; LN stats via shfl + statS.
// =====================================================================
__global__ __launch_bounds__(512, 4) void k1_sage(
    const float* __restrict__ iq,
    const float* __restrict__ Wl0, const float* __restrict__ bl0, const float* __restrict__ Wr0,
    const unsigned short* __restrict__ wbf,
    const float* __restrict__ bl12,
    const float* __restrict__ lng, const float* __restrict__ lnb,
    float* __restrict__ pf)
{
    __shared__ unsigned short hS[128][136];    // 34 KB  (h master, bf16)
    __shared__ unsigned short aggS[128][136];  // 34 KB
    __shared__ float statS[128][4];            // {sum_wc0, sq_wc0, sum_wc1, sq_wc1}
    __shared__ float xS[128][2], axS[128][2];

    const int t  = threadIdx.x;
    const int l  = t & 63;
    const int w  = t >> 6;
    const int wr = w >> 1;        // 0..3  (row group of 32)
    const int wc = w & 1;         // 0..1  (col group of 64)
    const int g0 = blockIdx.x * 16;

    // ---- patchify (16 graphs x 8 nodes x 2 ch) ----
    if (t < 256) {
        int r = t >> 1, c = t & 1;
        int gid  = g0 + (r >> 3);
        int node = r & 7;
        int b = gid / 31, p = gid - b * 31;
        xS[r][c] = iq[((size_t)b * 2 + c) * 128 + p * 4 + node];
    }
    __syncthreads();
    if (t < 256) {
        int r = t >> 1, c = t & 1;
        int node = r & 7, base = r & ~7;
        float s = 0.f;
        #pragma unroll
        for (int j = 0; j < 8; ++j) s += adjW(node, j) * xS[base + j][c];
        axS[r][c] = s;
    }
    __syncthreads();

    // ---- layer 0 (K=2) + LN + relu, row-per-thread layout ----
    {
        const int r = t >> 2, cb = (t & 3) * 32;
        const float a0 = axS[r][0], a1 = axS[r][1];
        const float x0 = xS[r][0],  x1 = xS[r][1];
        float ov[32];
        float s = 0.f, s2 = 0.f;
        #pragma unroll
        for (int i = 0; i < 32; ++i) {
            int o = cb + i;
            float2 wl  = *(const float2*)(Wl0 + o * 2);
            float2 wr_ = *(const float2*)(Wr0 + o * 2);
            float v = bl0[o] + a0 * wl.x + a1 * wl.y + x0 * wr_.x + x1 * wr_.y;
            ov[i] = v; s += v; s2 += v * v;
        }
        s  += __shfl_xor(s, 1, 64);  s2 += __shfl_xor(s2, 1, 64);
        s  += __shfl_xor(s, 2, 64);  s2 += __shfl_xor(s2, 2, 64);
        const float mu   = s * (1.f / 128.f);
        const float var  = s2 * (1.f / 128.f) - mu * mu;
        const float rstd = rsqrtf(var + 1e-5f);
        #pragma unroll
        for (int i = 0; i < 32; ++i) {
            int o = cb + i;
            float v = (ov[i] - mu) * rstd * lng[o] + lnb[o];
            hS[r][o] = f2bf(fmaxf(v, 0.f));
        }
    }
    __syncthreads();

    // ---- layers 1,2 : MFMA ----
    #pragma unroll 1
    for (int lay = 0; lay < 2; ++lay) {
        // agg pass (per-thread, K=8): aggS = blockdiag(A) @ hS
        {
            const int gi = t >> 5, c0 = t & 31;
            #pragma unroll
            for (int k = 0; k < 4; ++k) {
                int c = c0 + 32 * k;
                float hv[8];
                #pragma unroll
                for (int j = 0; j < 8; ++j) hv[j] = bf2f(hS[gi * 8 + j][c]);
                #pragma unroll
                for (int i = 0; i < 8; ++i) {
                    float s = 0.f;
                    #pragma unroll
                    for (int j = 0; j < 8; ++j) s += adjW(i, j) * hv[j];
                    aggS[gi * 8 + i][c] = f2bf(s);
                }
            }
        }
        __syncthreads();

        const unsigned short* wl  = wbf + lay * 16384;           // [o][f] bf16
        const unsigned short* wrp = wbf + 32768 + lay * 16384;

        f32x4 acc[2][4];
        #pragma unroll
        for (int mt = 0; mt < 2; ++mt)
            #pragma unroll
            for (int nt = 0; nt < 4; ++nt) acc[mt][nt] = (f32x4){0.f, 0.f, 0.f, 0.f};

        const int rfrag = wr * 32 + (l & 15);
        const int kgrp  = (l >> 4) * 8;
        #pragma unroll
        for (int ks = 0; ks < 4; ++ks) {
            const int kb = ks * 32 + kgrp;
            bf16x8 aA[2], aH[2];
            #pragma unroll
            for (int mt = 0; mt < 2; ++mt) {
                aA[mt] = *(const bf16x8*)&aggS[rfrag + mt * 16][kb];
                aH[mt] = *(const bf16x8*)&hS[rfrag + mt * 16][kb];
            }
            #pragma unroll
            for (int nt = 0; nt < 4; ++nt) {
                const int col = wc * 64 + nt * 16 + (l & 15);
                bf16x8 bL = *(const bf16x8*)&wl[col * 128 + kb];
                bf16x8 bR = *(const bf16x8*)&wrp[col * 128 + kb];
                #pragma unroll
                for (int mt = 0; mt < 2; ++mt) {
                    acc[mt][nt] = __builtin_amdgcn_mfma_f32_16x16x32_bf16(aA[mt], bL, acc[mt][nt], 0, 0, 0);
                    acc[mt][nt] = __builtin_amdgcn_mfma_f32_16x16x32_bf16(aH[mt], bR, acc[mt][nt], 0, 0, 0);
                }
            }
        }

        // bias + LN stats (C-frag layout: row=(l>>4)*4+q (+16mt+32wr), col=(l&15)+16nt+64wc)
        float bias[4];
        #pragma unroll
        for (int nt = 0; nt < 4; ++nt) bias[nt] = bl12[lay * 128 + wc * 64 + nt * 16 + (l & 15)];
        float rs[2][4], rq[2][4];
        #pragma unroll
        for (int mt = 0; mt < 2; ++mt) {
            #pragma unroll
            for (int q = 0; q < 4; ++q) { rs[mt][q] = 0.f; rq[mt][q] = 0.f; }
            #pragma unroll
            for (int nt = 0; nt < 4; ++nt)
                #pragma unroll
                for (int q = 0; q < 4; ++q) {
                    float v = acc[mt][nt][q] + bias[nt];
                    acc[mt][nt][q] = v;
                    rs[mt][q] += v; rq[mt][q] += v * v;
                }
            #pragma unroll
            for (int q = 0; q < 4; ++q)
                #pragma unroll
                for (int m = 1; m < 16; m <<= 1) {
                    rs[mt][q] += __shfl_xor(rs[mt][q], m, 64);
                    rq[mt][q] += __shfl_xor(rq[mt][q], m, 64);
                }
        }
        if ((l & 15) == 0) {
            #pragma unroll
            for (int mt = 0; mt < 2; ++mt)
                #pragma unroll
                for (int q = 0; q < 4; ++q) {
                    int row = wr * 32 + mt * 16 + (l >> 4) * 4 + q;
                    statS[row][wc * 2]     = rs[mt][q];
                    statS[row][wc * 2 + 1] = rq[mt][q];
                }
        }
        __syncthreads();   // stats ready; also: all MFMA reads of hS complete

        // normalize + relu + residual -> hS (bf16 master)
        const float* lg = lng + (lay + 1) * 128;
        const float* lb = lnb + (lay + 1) * 128;
        float gam[4], bet[4];
        #pragma unroll
        for (int nt = 0; nt < 4; ++nt) {
            int col = wc * 64 + nt * 16 + (l & 15);
            gam[nt] = lg[col]; bet[nt] = lb[col];
        }
        #pragma unroll
        for (int mt = 0; mt < 2; ++mt)
            #pragma unroll
            for (int q = 0; q < 4; ++q) {
                int row = wr * 32 + mt * 16 + (l >> 4) * 4 + q;
                float4 st = *(const float4*)&statS[row][0];
                float sum = st.x + st.z, sq = st.y + st.w;
                float mu   = sum * (1.f / 128.f);
                float var  = sq * (1.f / 128.f) - mu * mu;
                float rstd = rsqrtf(var + 1e-5f);
                #pragma unroll
                for (int nt = 0; nt < 4; ++nt) {
                    int col = wc * 64 + nt * 16 + (l & 15);
                    float v = (acc[mt][nt][q] - mu) * rstd * gam[nt] + bet[nt];
                    float h = bf2f(hS[row][col]) + fmaxf(v, 0.f);
                    hS[row][col] = f2bf(h);
                }
            }
        __syncthreads();
    }

    // ---- node mean -> patch features (fp32 out) ----
    {
        const int gi = t >> 5, c0 = t & 31;
        #pragma unroll
        for (int k = 0; k < 4; ++k) {
            int c = c0 + 32 * k;
            float s = 0.f;
            #pragma unroll
            for (int j = 0; j < 8; ++j) s += bf2f(hS[gi * 8 + j][c]);
            pf[(size_t)(g0 + gi) * 128 + c] = s * 0.125f;
        }
    }
}

// =====================================================================
// K2: xg = src(M=63488,128) @ w_ih^T(384,128) + b_ih  -> bf16
// =====================================================================
__global__ __launch_bounds__(256) void k2_xg(
    const float* __restrict__ src, const float* __restrict__ W,
    const float* __restrict__ bias, unsigned short* __restrict__ out)
{
    __shared__ float At[128 * 132];
    __shared__ float Bt[128 * 132];
    const int t  = threadIdx.x;
    const int m0 = blockIdx.x * 128;
    const int n0 = blockIdx.y * 128;

    #pragma unroll
    for (int i = 0; i < 16; ++i) {
        int idx4 = t + 256 * i;
        int r = idx4 >> 5, f = (idx4 & 31) << 2;
        *(float4*)(&At[r * 132 + f]) = *(const float4*)(src + (size_t)(m0 + r) * 128 + f);
        *(float4*)(&Bt[r * 132 + f]) = *(const float4*)(W + (size_t)(n0 + r) * 128 + f);
    }
    __syncthreads();

    const int ty = t >> 4, tx = t & 15;
    float acc[8][8];
    #pragma unroll
    for (int i = 0; i < 8; ++i)
        #pragma unroll
        for (int j = 0; j < 8; ++j) acc[i][j] = 0.f;

    #pragma unroll 4
    for (int f4 = 0; f4 < 32; ++f4) {
        const int f = f4 << 2;
        float4 a[8];
        #pragma unroll
        for (int i = 0; i < 8; ++i) a[i] = *(const float4*)(&At[(ty + 16 * i) * 132 + f]);
        #pragma unroll
        for (int j = 0; j < 8; ++j) {
            const float4 b = *(const float4*)(&Bt[(tx + 16 * j) * 132 + f]);
            #pragma unroll
            for (int i = 0; i < 8; ++i)
                acc[i][j] += a[i].x * b.x + a[i].y * b.y + a[i].z * b.z + a[i].w * b.w;
        }
    }
    #pragma unroll
    for (int j = 0; j < 8; ++j) {
        int n = n0 + tx + 16 * j;
        float bv = bias[n];
        #pragma unroll
        for (int i = 0; i < 8; ++i) {
            int m = m0 + ty + 16 * i;
            out[(size_t)m * 384 + n] = f2bf(acc[i][j] + bv);
        }
    }
}

// =====================================================================
// K3: GRU layer, 31 timesteps in-kernel.
// =====================================================================
__global__ __launch_bounds__(512) void k3_gru(
    const unsigned short* __restrict__ xg, const float* __restrict__ whh,
    const float* __restrict__ bhh, float* __restrict__ o1, float* __restrict__ gout)
{
    __shared__ unsigned short wS[384 * 132];   // ~99 KB
    __shared__ float hS[8][128];               // 4 KB

    const int t = threadIdx.x;
    #pragma unroll
    for (int i = 0; i < 24; ++i) {
        int idx4 = t + 512 * i;                // 0..12287
        int j = idx4 >> 5, f = (idx4 & 31) << 2;
        float4 v = *(const float4*)(whh + (size_t)j * 128 + f);
        unsigned int p0 = (unsigned int)f2bf(v.x) | ((unsigned int)f2bf(v.y) << 16);
        unsigned int p1 = (unsigned int)f2bf(v.z) | ((unsigned int)f2bf(v.w) << 16);
        *(unsigned int*)(&wS[j * 132 + f])     = p0;
        *(unsigned int*)(&wS[j * 132 + f + 2]) = p1;
    }
    ((float*)hS)[t] = 0.f;
    ((float*)hS)[t + 512] = 0.f;

    const int rp = t >> 7;
    const int o  = t & 127;
    const int r0 = rp, r1 = rp + 4;
    const int b0 = blockIdx.x * 8;

    float bh[3];
    #pragma unroll
    for (int gg = 0; gg < 3; ++gg) bh[gg] = bhh[gg * 128 + o];

    const size_t xrow0 = (size_t)(b0 + r0) * 31 * 384;
    const size_t xrow1 = (size_t)(b0 + r1) * 31 * 384;
    __syncthreads();

    for (int ts = 0; ts < 31; ++ts) {
        float a0[3] = {0.f, 0.f, 0.f}, a1[3] = {0.f, 0.f, 0.f};
        #pragma unroll 4
        for (int f4 = 0; f4 < 32; ++f4) {
            const int f = f4 << 2;
            const float4 h0 = *(const float4*)(&hS[r0][f]);
            const float4 h1 = *(const float4*)(&hS[r1][f]);
            #pragma unroll
            for (int gg = 0; gg < 3; ++gg) {
                const uint2 w = *(const uint2*)(&wS[(gg * 128 + o) * 132 + f]);
                const float w0 = bflo(w.x), w1 = bfhi(w.x);
                const float w2 = bflo(w.y), w3 = bfhi(w.y);
                a0[gg] += h0.x * w0 + h0.y * w1 + h0.z * w2 + h0.w * w3;
                a1[gg] += h1.x * w0 + h1.y * w1 + h1.z * w2 + h1.w * w3;
            }
        }
        const size_t xb0 = xrow0 + (size_t)ts * 384;
        const size_t xb1 = xrow1 + (size_t)ts * 384;
        float hnew0, hnew1;
        {
            float xr = bf2f(xg[xb0 + o]), xz = bf2f(xg[xb0 + 128 + o]), xn = bf2f(xg[xb0 + 256 + o]);
            float r = sigm(xr + a0[0] + bh[0]);
            float z = sigm(xz + a0[1] + bh[1]);
            float nn = tanh_(xn + r * (a0[2] + bh[2]));
            float hp = hS[r0][o];
            hnew0 = (1.f - z) * nn + z * hp;
        }
        {
            float xr = bf2f(xg[xb1 + o]), xz = bf2f(xg[xb1 + 128 + o]), xn = bf2f(xg[xb1 + 256 + o]);
            float r = sigm(xr + a1[0] + bh[0]);
            float z = sigm(xz + a1[1] + bh[1]);
            float nn = tanh_(xn + r * (a1[2] + bh[2]));
            float hp = hS[r1][o];
            hnew1 = (1.f - z) * nn + z * hp;
        }
        __syncthreads();
        hS[r0][o] = hnew0;
        hS[r1][o] = hnew1;
        if (o1 != nullptr) {
            o1[((size_t)(b0 + r0) * 31 + ts) * 128 + o] = hnew0;
            o1[((size_t)(b0 + r1) * 31 + ts) * 128 + o] = hnew1;
        }
        if (gout != nullptr && ts == 30) {
            gout[(size_t)(b0 + r0) * 128 + o] = hnew0;
            gout[(size_t)(b0 + r1) * 128 + o] = hnew1;
        }
        __syncthreads();
    }
}

// =====================================================================
// K4: logits = g(2048,128) @ etf(128,8)
// =====================================================================
__global__ __launch_bounds__(256) void k4_logits(
    const float* __restrict__ g, const float* __restrict__ etf, float* __restrict__ logits)
{
    const int idx = blockIdx.x * 256 + threadIdx.x;
    const int b = idx >> 3, c = idx & 7;
    float s = 0.f;
    #pragma unroll 8
    for (int f = 0; f < 128; ++f) s += g[(size_t)b * 128 + f] * etf[f * 8 + c];
    logits[idx] = s;
}

// =====================================================================
extern "C" void kernel_launch(void* const* d_in, const int* in_sizes, int n_in,
                              void* d_out, int out_size, void* d_ws, size_t ws_size,
                              hipStream_t stream) {
    const float* iq   = (const float*)d_in[0];
    const float* Wl0  = (const float*)d_in[1];
    const float* bl0  = (const float*)d_in[2];
    const float* Wr0  = (const float*)d_in[3];
    const float* Wl12 = (const float*)d_in[4];
    const float* bl12 = (const float*)d_in[5];
    const float* Wr12 = (const float*)d_in[6];
    const float* lng  = (const float*)d_in[7];
    const float* lnb  = (const float*)d_in[8];
    const float* wih  = (const float*)d_in[9];
    const float* whh  = (const float*)d_in[10];
    const float* bih  = (const float*)d_in[11];
    const float* bhh  = (const float*)d_in[12];
    const float* etf  = (const float*)d_in[13];

    float* out    = (float*)d_out;
    float* logits = out;                       // 2048*8
    float* gbuf   = out + 16384;               // 2048*128
    float* pf     = out + 16384 + 262144;      // 63488*128

    // ws: [wbf bf16 weights 131072 B, then overwritten by xg] xg bf16 (48758784 B), o1 fp32
    unsigned short* wbf = (unsigned short*)d_ws;
    unsigned short* xg  = (unsigned short*)d_ws;
    float* o1 = (float*)((char*)d_ws + 48758784);

    // 0) weights -> bf16 (rewritten every replay; xg overwrites later)
    k0_wconv<<<256, 256, 0, stream>>>(Wl12, Wr12, wbf);
    // 1) fused graph stage -> patch_features
    k1_sage<<<3968, 512, 0, stream>>>(iq, Wl0, bl0, Wr0, wbf, bl12, lng, lnb, pf);
    // 2) GRU layer 1
    k2_xg<<<dim3(496, 3), 256, 0, stream>>>(pf, wih, bih, xg);
    k3_gru<<<256, 512, 0, stream>>>(xg, whh, bhh, o1, nullptr);
    // 3) GRU layer 2
    k2_xg<<<dim3(496, 3), 256, 0, stream>>>(o1, wih + 49152, bih + 384, xg);
    k3_gru<<<256, 512, 0, stream>>>(xg, whh + 49152, bhh + 384, nullptr, gbuf);
    // 4) logits
    k4_logits<<<64, 256, 0, stream>>>(gbuf, etf, logits);
}

// Round 3
// 719.893 us; speedup vs baseline: 3.4802x; 1.5296x over previous
//
#include <hip/hip_runtime.h>
#include <hip/hip_bf16.h>

typedef __attribute__((ext_vector_type(8))) short bf16x8;
typedef __attribute__((ext_vector_type(4))) float f32x4;

// ---------- helpers ----------
__device__ __forceinline__ unsigned short f2bf(float v) {
    union { __hip_bfloat16 h; unsigned short u; } cv;
    cv.h = __float2bfloat16(v);           // hw RNE convert
    return cv.u;
}
__device__ __forceinline__ float bf2f(unsigned short u) {
    return __uint_as_float(((unsigned int)u) << 16);
}
__device__ __forceinline__ float sigm(float x) { return 1.f / (1.f + __expf(-x)); }
__device__ __forceinline__ float tanh_(float x) { return 2.f / (1.f + __expf(-2.f * x)) - 1.f; }
__device__ __forceinline__ float adjW(int i, int j) {
    const float inv[8] = {1.f/4.f, 1.f/5.f, 1.f/6.f, 1.f/7.f,
                          1.f/7.f, 1.f/6.f, 1.f/5.f, 1.f/4.f};
    int d = i - j; d = d < 0 ? -d : d;
    return (d >= 1 && d <= 4) ? inv[i] : 0.f;
}

// =====================================================================
// K0: convert weights to bf16 into ws.
// layout (u16 elems): [0 Wl12 32768][32768 Wr12 32768][65536 wih 98304][163840 whh 98304]
// =====================================================================
__global__ __launch_bounds__(256) void k0_wconv(const float* __restrict__ Wl12,
    const float* __restrict__ Wr12, const float* __restrict__ wih,
    const float* __restrict__ whh, unsigned short* __restrict__ wbf)
{
    int i = blockIdx.x * 256 + threadIdx.x;   // 0..262143
    float v;
    if (i < 32768)       v = Wl12[i];
    else if (i < 65536)  v = Wr12[i - 32768];
    else if (i < 163840) v = wih[i - 65536];
    else                 v = whh[i - 163840];
    wbf[i] = f2bf(v);
}

// =====================================================================
// K1: fused graph stage, MFMA, adjacency folded into C-frag epilogue.
// 512 thr (8 waves = 4 wr x 2 wc), 16 graphs (128 rows).
// =====================================================================
__global__ __launch_bounds__(512, 2) void k1_sage(
    const float* __restrict__ iq,
    const float* __restrict__ Wl0, const float* __restrict__ bl0, const float* __restrict__ Wr0,
    const unsigned short* __restrict__ wbf,
    const float* __restrict__ bl12,
    const float* __restrict__ lng, const float* __restrict__ lnb,
    float* __restrict__ pf)
{
    __shared__ unsigned short hS[128][136];    // 34 KB
    __shared__ float statS[128][4];
    __shared__ float xS[128][2], axS[128][2];

    const int t  = threadIdx.x;
    const int l  = t & 63;
    const int w  = t >> 6;
    const int wr = w >> 1, wc = w & 1;
    const int lc = l & 15, li = l >> 4;
    const int g0 = blockIdx.x * 16;

    // ---- patchify ----
    if (t < 256) {
        int r = t >> 1, c = t & 1;
        int gid = g0 + (r >> 3);
        int node = r & 7;
        int b = gid / 31, p = gid - b * 31;
        xS[r][c] = iq[((size_t)b * 2 + c) * 128 + p * 4 + node];
    }
    __syncthreads();
    if (t < 256) {
        int r = t >> 1, c = t & 1;
        int node = r & 7, base = r & ~7;
        float s = 0.f;
        #pragma unroll
        for (int j = 0; j < 8; ++j) s += adjW(node, j) * xS[base + j][c];
        axS[r][c] = s;
    }
    __syncthreads();

    // ---- layer 0 (K=2) + LN + relu ----
    {
        const int r = t >> 2, cb = (t & 3) * 32;
        const float a0 = axS[r][0], a1 = axS[r][1];
        const float x0 = xS[r][0],  x1 = xS[r][1];
        float ov[32];
        float s = 0.f, s2 = 0.f;
        #pragma unroll
        for (int i = 0; i < 32; ++i) {
            int o = cb + i;
            float2 wl  = *(const float2*)(Wl0 + o * 2);
            float2 wr_ = *(const float2*)(Wr0 + o * 2);
            float v = bl0[o] + a0 * wl.x + a1 * wl.y + x0 * wr_.x + x1 * wr_.y;
            ov[i] = v; s += v; s2 += v * v;
        }
        s  += __shfl_xor(s, 1, 64);  s2 += __shfl_xor(s2, 1, 64);
        s  += __shfl_xor(s, 2, 64);  s2 += __shfl_xor(s2, 2, 64);
        const float mu   = s * (1.f / 128.f);
        const float var  = s2 * (1.f / 128.f) - mu * mu;
        const float rstd = rsqrtf(var + 1e-5f);
        #pragma unroll
        for (int i = 0; i < 32; ++i) {
            int o = cb + i;
            float v = (ov[i] - mu) * rstd * lng[o] + lnb[o];
            hS[r][o] = f2bf(fmaxf(v, 0.f));
        }
    }
    __syncthreads();

    // ---- layers 1,2 ----
    const int rfrag = wr * 32 + lc;
    const int kgrp  = li * 8;
    const int half  = li & 1;

    #pragma unroll 1
    for (int lay = 0; lay < 2; ++lay) {
        const unsigned short* wl  = wbf + lay * 16384;
        const unsigned short* wrp = wbf + 32768 + lay * 16384;

        f32x4 acc[2][4];
        #pragma unroll
        for (int mt = 0; mt < 2; ++mt)
            #pragma unroll
            for (int nt = 0; nt < 4; ++nt) acc[mt][nt] = (f32x4){0.f, 0.f, 0.f, 0.f};

        // pass 1: Y1 = h @ Wl^T
        #pragma unroll
        for (int ks = 0; ks < 4; ++ks) {
            const int kb = ks * 32 + kgrp;
            bf16x8 aH0 = *(const bf16x8*)&hS[rfrag][kb];
            bf16x8 aH1 = *(const bf16x8*)&hS[rfrag + 16][kb];
            #pragma unroll
            for (int nt = 0; nt < 4; ++nt) {
                const int col = wc * 64 + nt * 16 + lc;
                bf16x8 b = *(const bf16x8*)&wl[col * 128 + kb];
                acc[0][nt] = __builtin_amdgcn_mfma_f32_16x16x32_bf16(aH0, b, acc[0][nt], 0, 0, 0);
                acc[1][nt] = __builtin_amdgcn_mfma_f32_16x16x32_bf16(aH1, b, acc[1][nt], 0, 0, 0);
            }
        }

        // A-apply in C-frag regs: graph rows0-7 split across lane pair (l, l^16)
        #pragma unroll
        for (int mt = 0; mt < 2; ++mt)
            #pragma unroll
            for (int nt = 0; nt < 4; ++nt) {
                float own[4], oth[4];
                #pragma unroll
                for (int q = 0; q < 4; ++q) {
                    own[q] = acc[mt][nt][q];
                    oth[q] = __shfl_xor(own[q], 16, 64);
                }
                float yL[4], yH[4];
                #pragma unroll
                for (int q = 0; q < 4; ++q) {
                    yL[q] = half ? oth[q] : own[q];
                    yH[q] = half ? own[q] : oth[q];
                }
                float S = yL[0]+yL[1]+yL[2]+yL[3]+yH[0]+yH[1]+yH[2]+yH[3];
                float o0, o1, o2, o3;
                if (!half) {
                    o0 = (S - yL[0] - yH[1] - yH[2] - yH[3]) * 0.25f;
                    o1 = (S - yL[1] - yH[2] - yH[3]) * 0.2f;
                    o2 = (S - yL[2] - yH[3]) * (1.f/6.f);
                    o3 = (S - yL[3]) * (1.f/7.f);
                } else {
                    o0 = (S - yH[0]) * (1.f/7.f);
                    o1 = (S - yH[1] - yL[0]) * (1.f/6.f);
                    o2 = (S - yH[2] - yL[0] - yL[1]) * 0.2f;
                    o3 = (S - yH[3] - yL[0] - yL[1] - yL[2]) * 0.25f;
                }
                acc[mt][nt][0] = o0; acc[mt][nt][1] = o1;
                acc[mt][nt][2] = o2; acc[mt][nt][3] = o3;
            }

        // pass 2: acc += h @ Wr^T
        #pragma unroll
        for (int ks = 0; ks < 4; ++ks) {
            const int kb = ks * 32 + kgrp;
            bf16x8 aH0 = *(const bf16x8*)&hS[rfrag][kb];
            bf16x8 aH1 = *(const bf16x8*)&hS[rfrag + 16][kb];
            #pragma unroll
            for (int nt = 0; nt < 4; ++nt) {
                const int col = wc * 64 + nt * 16 + lc;
                bf16x8 b = *(const bf16x8*)&wrp[col * 128 + kb];
                acc[0][nt] = __builtin_amdgcn_mfma_f32_16x16x32_bf16(aH0, b, acc[0][nt], 0, 0, 0);
                acc[1][nt] = __builtin_amdgcn_mfma_f32_16x16x32_bf16(aH1, b, acc[1][nt], 0, 0, 0);
            }
        }

        // bias + LN stats
        float bias[4];
        #pragma unroll
        for (int nt = 0; nt < 4; ++nt) bias[nt] = bl12[lay * 128 + wc * 64 + nt * 16 + lc];
        float rs[2][4], rq[2][4];
        #pragma unroll
        for (int mt = 0; mt < 2; ++mt) {
            #pragma unroll
            for (int q = 0; q < 4; ++q) { rs[mt][q] = 0.f; rq[mt][q] = 0.f; }
            #pragma unroll
            for (int nt = 0; nt < 4; ++nt)
                #pragma unroll
                for (int q = 0; q < 4; ++q) {
                    float v = acc[mt][nt][q] + bias[nt];
                    acc[mt][nt][q] = v;
                    rs[mt][q] += v; rq[mt][q] += v * v;
                }
            #pragma unroll
            for (int q = 0; q < 4; ++q)
                #pragma unroll
                for (int m = 1; m < 16; m <<= 1) {
                    rs[mt][q] += __shfl_xor(rs[mt][q], m, 64);
                    rq[mt][q] += __shfl_xor(rq[mt][q], m, 64);
                }
        }
        if (lc == 0) {
            #pragma unroll
            for (int mt = 0; mt < 2; ++mt)
                #pragma unroll
                for (int q = 0; q < 4; ++q) {
                    int row = wr * 32 + mt * 16 + li * 4 + q;
                    statS[row][wc * 2]     = rs[mt][q];
                    statS[row][wc * 2 + 1] = rq[mt][q];
                }
        }
        __syncthreads();   // stats ready; all MFMA reads of hS done

        // normalize + relu + residual RMW -> hS
        const float* lg = lng + (lay + 1) * 128;
        const float* lb = lnb + (lay + 1) * 128;
        float gam[4], bet[4];
        #pragma unroll
        for (int nt = 0; nt < 4; ++nt) {
            int col = wc * 64 + nt * 16 + lc;
            gam[nt] = lg[col]; bet[nt] = lb[col];
        }
        #pragma unroll
        for (int mt = 0; mt < 2; ++mt)
            #pragma unroll
            for (int q = 0; q < 4; ++q) {
                int row = wr * 32 + mt * 16 + li * 4 + q;
                float4 st = *(const float4*)&statS[row][0];
                float sum = st.x + st.z, sq = st.y + st.w;
                float mu   = sum * (1.f / 128.f);
                float var  = sq * (1.f / 128.f) - mu * mu;
                float rstd = rsqrtf(var + 1e-5f);
                #pragma unroll
                for (int nt = 0; nt < 4; ++nt) {
                    int col = wc * 64 + nt * 16 + lc;
                    float v = (acc[mt][nt][q] - mu) * rstd * gam[nt] + bet[nt];
                    float h = bf2f(hS[row][col]) + fmaxf(v, 0.f);
                    hS[row][col] = f2bf(h);
                }
            }
        __syncthreads();
    }

    // ---- node mean -> patch features ----
    {
        const int gi = t >> 5, c0 = t & 31;
        #pragma unroll
        for (int k = 0; k < 4; ++k) {
            int c = c0 + 32 * k;
            float s = 0.f;
            #pragma unroll
            for (int j = 0; j < 8; ++j) s += bf2f(hS[gi * 8 + j][c]);
            pf[(size_t)(g0 + gi) * 128 + c] = s * 0.125f;
        }
    }
}

// =====================================================================
// K2: xg1 = pf(63488,128) @ wih1^T(384,128) + bih1 -> bf16.  MFMA, no LDS.
// block 256 (4 waves x 16 rows), grid 992.
// =====================================================================
__global__ __launch_bounds__(256) void k2_xg(
    const float* __restrict__ src, const unsigned short* __restrict__ wB,
    const float* __restrict__ bias, unsigned short* __restrict__ out)
{
    const int t = threadIdx.x, w = t >> 6, l = t & 63;
    const int lc = l & 15, li = l >> 4;
    const int m0 = blockIdx.x * 64 + w * 16;

    bf16x8 aA[4];
    #pragma unroll
    for (int ks = 0; ks < 4; ++ks) {
        const float* p = src + (size_t)(m0 + lc) * 128 + ks * 32 + li * 8;
        float4 f0 = *(const float4*)p;
        float4 f1 = *(const float4*)(p + 4);
        bf16x8 v;
        v[0] = (short)f2bf(f0.x); v[1] = (short)f2bf(f0.y);
        v[2] = (short)f2bf(f0.z); v[3] = (short)f2bf(f0.w);
        v[4] = (short)f2bf(f1.x); v[5] = (short)f2bf(f1.y);
        v[6] = (short)f2bf(f1.z); v[7] = (short)f2bf(f1.w);
        aA[ks] = v;
    }
    #pragma unroll 2
    for (int nt = 0; nt < 24; ++nt) {
        f32x4 acc = (f32x4){0.f, 0.f, 0.f, 0.f};
        #pragma unroll
        for (int ks = 0; ks < 4; ++ks) {
            bf16x8 b = *(const bf16x8*)&wB[(size_t)(nt * 16 + lc) * 128 + ks * 32 + li * 8];
            acc = __builtin_amdgcn_mfma_f32_16x16x32_bf16(aA[ks], b, acc, 0, 0, 0);
        }
        float bv = bias[nt * 16 + lc];
        #pragma unroll
        for (int q = 0; q < 4; ++q) {
            int m = m0 + li * 4 + q;
            out[(size_t)m * 384 + nt * 16 + lc] = f2bf(acc[q] + bv);
        }
    }
}

// =====================================================================
// K3: both GRU layers fused, 31 steps in-kernel, weights in registers.
// 256 blocks x 8 batch rows, 512 thr (8 waves); wave w owns cols 16w..16w+16.
// =====================================================================
__global__ __launch_bounds__(512, 2) void k3_gru(
    const unsigned short* __restrict__ xg, const unsigned short* __restrict__ wbf,
    const float* __restrict__ bih, const float* __restrict__ bhh,
    float* __restrict__ gbuf)
{
    __shared__ unsigned short h1S[16][136];
    __shared__ unsigned short h2S[16][136];

    const int t = threadIdx.x, w = t >> 6, l = t & 63;
    const int lc = l & 15, li = l >> 4;
    const int col = w * 16 + lc;          // 0..127
    const int kgrp = li * 8;
    const int b0 = blockIdx.x * 8;
    const bool act = (li < 2);

    // zero h state
    for (int i = t; i < 16 * 136; i += 512) {
        ((unsigned short*)h1S)[i] = 0;
        ((unsigned short*)h2S)[i] = 0;
    }

    // load weight fragments (B-operand: lane n=lc within tile, k-group kgrp)
    const unsigned short* wih2 = wbf + 114688;
    const unsigned short* whh1 = wbf + 163840;
    const unsigned short* whh2 = wbf + 212992;
    bf16x8 Wh1[3][4], Wi2[3][4], Wh2[3][4];
    #pragma unroll
    for (int g = 0; g < 3; ++g)
        #pragma unroll
        for (int ks = 0; ks < 4; ++ks) {
            size_t off = (size_t)(g * 128 + col) * 128 + ks * 32 + kgrp;
            Wh1[g][ks] = *(const bf16x8*)(whh1 + off);
            Wi2[g][ks] = *(const bf16x8*)(wih2 + off);
            Wh2[g][ks] = *(const bf16x8*)(whh2 + off);
        }
    float bh1[3], bi2[3], bh2[3];
    #pragma unroll
    for (int g = 0; g < 3; ++g) {
        bh1[g] = bhh[g * 128 + col];
        bi2[g] = bih[384 + g * 128 + col];
        bh2[g] = bhh[384 + g * 128 + col];
    }

    float h1r[4] = {0.f, 0.f, 0.f, 0.f};
    float h2r[4] = {0.f, 0.f, 0.f, 0.f};
    float x1[3][4];

    // prefetch xg1 for ts=0
    if (act) {
        #pragma unroll
        for (int g = 0; g < 3; ++g)
            #pragma unroll
            for (int q = 0; q < 4; ++q)
                x1[g][q] = bf2f(xg[((size_t)(b0 + li * 4 + q) * 31 + 0) * 384 + g * 128 + col]);
    }
    __syncthreads();

    for (int ts = 0; ts < 31; ++ts) {
        // ---- layer1 hidden matmul (h1S old) ----
        bf16x8 aH[4];
        #pragma unroll
        for (int ks = 0; ks < 4; ++ks) aH[ks] = *(const bf16x8*)&h1S[lc][ks * 32 + kgrp];
        f32x4 acc[3];
        #pragma unroll
        for (int g = 0; g < 3; ++g) {
            acc[g] = (f32x4){0.f, 0.f, 0.f, 0.f};
            #pragma unroll
            for (int ks = 0; ks < 4; ++ks)
                acc[g] = __builtin_amdgcn_mfma_f32_16x16x32_bf16(aH[ks], Wh1[g][ks], acc[g], 0, 0, 0);
        }
        // prefetch next step's xg1 (hide HBM latency under gates+barriers)
        float xn[3][4];
        if (act && ts < 30) {
            #pragma unroll
            for (int g = 0; g < 3; ++g)
                #pragma unroll
                for (int q = 0; q < 4; ++q)
                    xn[g][q] = bf2f(xg[((size_t)(b0 + li * 4 + q) * 31 + ts + 1) * 384 + g * 128 + col]);
        }
        // ---- layer1 gates ----
        if (act) {
            #pragma unroll
            for (int q = 0; q < 4; ++q) {
                float r  = sigm(x1[0][q] + acc[0][q] + bh1[0]);
                float z  = sigm(x1[1][q] + acc[1][q] + bh1[1]);
                float nn = tanh_(x1[2][q] + r * (acc[2][q] + bh1[2]));
                h1r[q] = (1.f - z) * nn + z * h1r[q];
            }
        }
        __syncthreads();                       // all aH reads of old h1S done
        if (act) {
            #pragma unroll
            for (int q = 0; q < 4; ++q) h1S[li * 4 + q][col] = f2bf(h1r[q]);
        }
        __syncthreads();                       // new h1 visible

        // ---- xg2 = h1new @ wih2^T + bih2 ; layer2 hidden matmul (h2S old) ----
        bf16x8 aH1n[4], aH2[4];
        #pragma unroll
        for (int ks = 0; ks < 4; ++ks) {
            aH1n[ks] = *(const bf16x8*)&h1S[lc][ks * 32 + kgrp];
            aH2[ks]  = *(const bf16x8*)&h2S[lc][ks * 32 + kgrp];
        }
        f32x4 ax2[3], ah2[3];
        #pragma unroll
        for (int g = 0; g < 3; ++g) {
            ax2[g] = (f32x4){0.f, 0.f, 0.f, 0.f};
            ah2[g] = (f32x4){0.f, 0.f, 0.f, 0.f};
            #pragma unroll
            for (int ks = 0; ks < 4; ++ks) {
                ax2[g] = __builtin_amdgcn_mfma_f32_16x16x32_bf16(aH1n[ks], Wi2[g][ks], ax2[g], 0, 0, 0);
                ah2[g] = __builtin_amdgcn_mfma_f32_16x16x32_bf16(aH2[ks],  Wh2[g][ks], ah2[g], 0, 0, 0);
            }
        }
        // ---- layer2 gates ----
        if (act) {
            #pragma unroll
            for (int q = 0; q < 4; ++q) {
                float xr = ax2[0][q] + bi2[0];
                float xz = ax2[1][q] + bi2[1];
                float xn2 = ax2[2][q] + bi2[2];
                float r  = sigm(xr + ah2[0][q] + bh2[0]);
                float z  = sigm(xz + ah2[1][q] + bh2[1]);
                float nn = tanh_(xn2 + r * (ah2[2][q] + bh2[2]));
                h2r[q] = (1.f - z) * nn + z * h2r[q];
            }
        }
        __syncthreads();                       // all aH2 reads of old h2S done
        if (act) {
            #pragma unroll
            for (int q = 0; q < 4; ++q) h2S[li * 4 + q][col] = f2bf(h2r[q]);
        }
        __syncthreads();                       // new h2 visible

        // rotate prefetched xg1
        #pragma unroll
        for (int g = 0; g < 3; ++g)
            #pragma unroll
            for (int q = 0; q < 4; ++q) x1[g][q] = xn[g][q];
    }

    if (act) {
        #pragma unroll
        for (int q = 0; q < 4; ++q)
            gbuf[(size_t)(b0 + li * 4 + q) * 128 + col] = h2r[q];
    }
}

// =====================================================================
// K4: logits = g(2048,128) @ etf(128,8)
// =====================================================================
__global__ __launch_bounds__(256) void k4_logits(
    const float* __restrict__ g, const float* __restrict__ etf, float* __restrict__ logits)
{
    const int idx = blockIdx.x * 256 + threadIdx.x;
    const int b = idx >> 3, c = idx & 7;
    float s = 0.f;
    #pragma unroll 8
    for (int f = 0; f < 128; ++f) s += g[(size_t)b * 128 + f] * etf[f * 8 + c];
    logits[idx] = s;
}

// =====================================================================
extern "C" void kernel_launch(void* const* d_in, const int* in_sizes, int n_in,
                              void* d_out, int out_size, void* d_ws, size_t ws_size,
                              hipStream_t stream) {
    const float* iq   = (const float*)d_in[0];
    const float* Wl0  = (const float*)d_in[1];
    const float* bl0  = (const float*)d_in[2];
    const float* Wr0  = (const float*)d_in[3];
    const float* Wl12 = (const float*)d_in[4];
    const float* bl12 = (const float*)d_in[5];
    const float* Wr12 = (const float*)d_in[6];
    const float* lng  = (const float*)d_in[7];
    const float* lnb  = (const float*)d_in[8];
    const float* wih  = (const float*)d_in[9];
    const float* whh  = (const float*)d_in[10];
    const float* bih  = (const float*)d_in[11];
    const float* bhh  = (const float*)d_in[12];
    const float* etf  = (const float*)d_in[13];

    float* out    = (float*)d_out;
    float* logits = out;                       // 2048*8
    float* gbuf   = out + 16384;               // 2048*128
    float* pf     = out + 16384 + 262144;      // 63488*128

    // ws: [wbf 262144 u16 = 512KB][xg1 bf16 63488*384 u16 = 48.76MB]
    unsigned short* wbf = (unsigned short*)d_ws;
    unsigned short* xg  = wbf + 262144;

    k0_wconv<<<1024, 256, 0, stream>>>(Wl12, Wr12, wih, whh, wbf);
    k1_sage<<<3968, 512, 0, stream>>>(iq, Wl0, bl0, Wr0, wbf, bl12, lng, lnb, pf);
    k2_xg<<<992, 256, 0, stream>>>(pf, wbf + 65536, bih, xg);
    k3_gru<<<256, 512, 0, stream>>>(xg, wbf, bih, bhh, gbuf);
    k4_logits<<<64, 256, 0, stream>>>(gbuf, etf, logits);
}

// Round 4
// 417.986 us; speedup vs baseline: 5.9939x; 1.7223x over previous
//
#include <hip/hip_runtime.h>
#include <hip/hip_bf16.h>

typedef __attribute__((ext_vector_type(8))) short bf16x8;
typedef __attribute__((ext_vector_type(4))) float f32x4;

// ---------- helpers ----------
__device__ __forceinline__ unsigned short f2bf(float v) {
    union { __hip_bfloat16 h; unsigned short u; } cv;
    cv.h = __float2bfloat16(v);           // hw RNE convert
    return cv.u;
}
__device__ __forceinline__ float bf2f(unsigned short u) {
    return __uint_as_float(((unsigned int)u) << 16);
}
__device__ __forceinline__ float sigm(float x) { return 1.f / (1.f + __expf(-x)); }
__device__ __forceinline__ float tanh_(float x) { return 2.f / (1.f + __expf(-2.f * x)) - 1.f; }
__device__ __forceinline__ float adjW(int i, int j) {
    const float inv[8] = {1.f/4.f, 1.f/5.f, 1.f/6.f, 1.f/7.f,
                          1.f/7.f, 1.f/6.f, 1.f/5.f, 1.f/4.f};
    int d = i - j; d = d < 0 ? -d : d;
    return (d >= 1 && d <= 4) ? inv[i] : 0.f;
}
__device__ __forceinline__ bf16x8 addbf(bf16x8 a, bf16x8 b) {
    bf16x8 r;
    #pragma unroll
    for (int j = 0; j < 8; ++j)
        r[j] = (short)f2bf(bf2f((unsigned short)a[j]) + bf2f((unsigned short)b[j]));
    return r;
}

// =====================================================================
// K0: convert weights to bf16 into ws.
// layout (u16 elems): [0 Wl12 32768][32768 Wr12 32768][65536 wih 98304][163840 whh 98304]
// =====================================================================
__global__ __launch_bounds__(256) void k0_wconv(const float* __restrict__ Wl12,
    const float* __restrict__ Wr12, const float* __restrict__ wih,
    const float* __restrict__ whh, unsigned short* __restrict__ wbf)
{
    int i = blockIdx.x * 256 + threadIdx.x;   // 0..262143
    float v;
    if (i < 32768)       v = Wl12[i];
    else if (i < 65536)  v = Wr12[i - 32768];
    else if (i < 163840) v = wih[i - 65536];
    else                 v = whh[i - 163840];
    wbf[i] = f2bf(v);
}

// =====================================================================
// K1: fused graph stage. h in A-frag registers; weights LDS-staged per pass;
// hT = y transpose buffer. 512 thr (4 wr x 2 wc waves), 16 graphs/block.
// =====================================================================
__global__ __launch_bounds__(512, 4) void k1_sage(
    const float* __restrict__ iq,
    const float* __restrict__ Wl0, const float* __restrict__ bl0, const float* __restrict__ Wr0,
    const unsigned short* __restrict__ wbf,
    const float* __restrict__ bl12,
    const float* __restrict__ lng, const float* __restrict__ lnb,
    float* __restrict__ pf)
{
    __shared__ unsigned short wlds[128 * 136];   // 34816 B  weight buffer (bf16)
    __shared__ unsigned short hT[128][136];      // 34816 B  transpose buffer
    __shared__ float statS[128][4];
    __shared__ float xS[128][2], axS[128][2];
    __shared__ float w0l[256], w0r[256], w0b[128], w0g[128], w0bt[128];

    const int t  = threadIdx.x;
    const int l  = t & 63;
    const int w  = t >> 6;
    const int wr = w >> 1, wc = w & 1;
    const int lc = l & 15, li = l >> 4;
    const int kgrp = li * 8;
    const int half = li & 1;
    const int g0 = blockIdx.x * 16;

    // ---- prologue: patchify loads + w0 staging + stage Wl(layer1) ----
    if (t < 256) {
        int r = t >> 1, c = t & 1;
        int gid = g0 + (r >> 3);
        int node = r & 7;
        int b = gid / 31, p = gid - b * 31;
        xS[r][c] = iq[((size_t)b * 2 + c) * 128 + p * 4 + node];
        w0l[t] = Wl0[t];
        w0r[t] = Wr0[t];
    } else if (t < 384) {
        int o = t - 256;
        w0b[o]  = bl0[o];
        w0g[o]  = lng[o];
        w0bt[o] = lnb[o];
    }
    {   // stage Wl(lay=0) -> wlds
        #pragma unroll
        for (int i = 0; i < 4; ++i) {
            int c = i * 512 + t;               // 0..2047 chunks of 8 u16
            int col = c >> 4, kc = c & 15;
            uint4 v = *(const uint4*)(wbf + col * 128 + kc * 8);
            *(uint4*)&wlds[col * 136 + kc * 8] = v;
        }
    }
    __syncthreads();
    if (t < 256) {
        int r = t >> 1, c = t & 1;
        int node = r & 7, base = r & ~7;
        float s = 0.f;
        #pragma unroll
        for (int j = 0; j < 8; ++j) s += adjW(node, j) * xS[base + j][c];
        axS[r][c] = s;
    }
    __syncthreads();

    // ---- layer 0 (K=2) + LN + relu -> hT (bf16) ----
    {
        const int r = t >> 2, cb = (t & 3) * 32;
        const float a0 = axS[r][0], a1 = axS[r][1];
        const float x0 = xS[r][0],  x1 = xS[r][1];
        float ov[32];
        float s = 0.f, s2 = 0.f;
        #pragma unroll
        for (int i = 0; i < 32; ++i) {
            int o = cb + i;
            float v = w0b[o] + a0 * w0l[2*o] + a1 * w0l[2*o+1]
                             + x0 * w0r[2*o] + x1 * w0r[2*o+1];
            ov[i] = v; s += v; s2 += v * v;
        }
        s  += __shfl_xor(s, 1, 64);  s2 += __shfl_xor(s2, 1, 64);
        s  += __shfl_xor(s, 2, 64);  s2 += __shfl_xor(s2, 2, 64);
        const float mu   = s * (1.f / 128.f);
        const float var  = s2 * (1.f / 128.f) - mu * mu;
        const float rstd = rsqrtf(var + 1e-5f);
        #pragma unroll
        for (int j = 0; j < 4; ++j) {
            bf16x8 pk;
            #pragma unroll
            for (int i = 0; i < 8; ++i) {
                int o = cb + j * 8 + i;
                float v = (ov[j * 8 + i] - mu) * rstd * w0g[o] + w0bt[o];
                pk[i] = (short)f2bf(fmaxf(v, 0.f));
            }
            *(bf16x8*)&hT[r][cb + j * 8] = pk;
        }
    }
    __syncthreads();

    // ---- load h into A-frag registers ----
    bf16x8 hA[2][4];
    #pragma unroll
    for (int mt = 0; mt < 2; ++mt)
        #pragma unroll
        for (int ks = 0; ks < 4; ++ks)
            hA[mt][ks] = *(const bf16x8*)&hT[wr * 32 + 16 * mt + lc][ks * 32 + kgrp];

    // ---- layers 1,2 ----
    #pragma unroll 1
    for (int lay = 0; lay < 2; ++lay) {
        f32x4 acc[2][4];
        #pragma unroll
        for (int mt = 0; mt < 2; ++mt)
            #pragma unroll
            for (int nt = 0; nt < 4; ++nt) acc[mt][nt] = (f32x4){0.f, 0.f, 0.f, 0.f};

        // pass 1: Y1 = h @ Wl^T   (wlds holds Wl(lay))
        #pragma unroll
        for (int ks = 0; ks < 4; ++ks) {
            #pragma unroll
            for (int nt = 0; nt < 4; ++nt) {
                const int col = wc * 64 + nt * 16 + lc;
                bf16x8 b = *(const bf16x8*)&wlds[col * 136 + ks * 32 + kgrp];
                acc[0][nt] = __builtin_amdgcn_mfma_f32_16x16x32_bf16(hA[0][ks], b, acc[0][nt], 0, 0, 0);
                acc[1][nt] = __builtin_amdgcn_mfma_f32_16x16x32_bf16(hA[1][ks], b, acc[1][nt], 0, 0, 0);
            }
        }

        // A-apply in C-frag regs (verified round 3)
        #pragma unroll
        for (int mt = 0; mt < 2; ++mt)
            #pragma unroll
            for (int nt = 0; nt < 4; ++nt) {
                float own[4], oth[4];
                #pragma unroll
                for (int q = 0; q < 4; ++q) {
                    own[q] = acc[mt][nt][q];
                    oth[q] = __shfl_xor(own[q], 16, 64);
                }
                float yL[4], yH[4];
                #pragma unroll
                for (int q = 0; q < 4; ++q) {
                    yL[q] = half ? oth[q] : own[q];
                    yH[q] = half ? own[q] : oth[q];
                }
                float S = yL[0]+yL[1]+yL[2]+yL[3]+yH[0]+yH[1]+yH[2]+yH[3];
                float o0, o1, o2, o3;
                if (!half) {
                    o0 = (S - yL[0] - yH[1] - yH[2] - yH[3]) * 0.25f;
                    o1 = (S - yL[1] - yH[2] - yH[3]) * 0.2f;
                    o2 = (S - yL[2] - yH[3]) * (1.f/6.f);
                    o3 = (S - yL[3]) * (1.f/7.f);
                } else {
                    o0 = (S - yH[0]) * (1.f/7.f);
                    o1 = (S - yH[1] - yL[0]) * (1.f/6.f);
                    o2 = (S - yH[2] - yL[0] - yL[1]) * 0.2f;
                    o3 = (S - yH[3] - yL[0] - yL[1] - yL[2]) * 0.25f;
                }
                acc[mt][nt][0] = o0; acc[mt][nt][1] = o1;
                acc[mt][nt][2] = o2; acc[mt][nt][3] = o3;
            }
        __syncthreads();                 // pass-1 wlds reads done

        // stage Wr(lay)
        {
            const unsigned short* mat = wbf + 32768 + lay * 16384;
            #pragma unroll
            for (int i = 0; i < 4; ++i) {
                int c = i * 512 + t;
                int col = c >> 4, kc = c & 15;
                uint4 v = *(const uint4*)(mat + col * 128 + kc * 8);
                *(uint4*)&wlds[col * 136 + kc * 8] = v;
            }
        }
        __syncthreads();                 // Wr ready

        // pass 2: acc += h @ Wr^T
        #pragma unroll
        for (int ks = 0; ks < 4; ++ks) {
            #pragma unroll
            for (int nt = 0; nt < 4; ++nt) {
                const int col = wc * 64 + nt * 16 + lc;
                bf16x8 b = *(const bf16x8*)&wlds[col * 136 + ks * 32 + kgrp];
                acc[0][nt] = __builtin_amdgcn_mfma_f32_16x16x32_bf16(hA[0][ks], b, acc[0][nt], 0, 0, 0);
                acc[1][nt] = __builtin_amdgcn_mfma_f32_16x16x32_bf16(hA[1][ks], b, acc[1][nt], 0, 0, 0);
            }
        }

        // bias + LN stats
        float bias[4];
        #pragma unroll
        for (int nt = 0; nt < 4; ++nt) bias[nt] = bl12[lay * 128 + wc * 64 + nt * 16 + lc];
        float rs[2][4], rq[2][4];
        #pragma unroll
        for (int mt = 0; mt < 2; ++mt) {
            #pragma unroll
            for (int q = 0; q < 4; ++q) { rs[mt][q] = 0.f; rq[mt][q] = 0.f; }
            #pragma unroll
            for (int nt = 0; nt < 4; ++nt)
                #pragma unroll
                for (int q = 0; q < 4; ++q) {
                    float v = acc[mt][nt][q] + bias[nt];
                    acc[mt][nt][q] = v;
                    rs[mt][q] += v; rq[mt][q] += v * v;
                }
            #pragma unroll
            for (int q = 0; q < 4; ++q)
                #pragma unroll
                for (int m = 1; m < 16; m <<= 1) {
                    rs[mt][q] += __shfl_xor(rs[mt][q], m, 64);
                    rq[mt][q] += __shfl_xor(rq[mt][q], m, 64);
                }
        }
        if (lc == 0) {
            #pragma unroll
            for (int mt = 0; mt < 2; ++mt)
                #pragma unroll
                for (int q = 0; q < 4; ++q) {
                    int row = wr * 32 + mt * 16 + li * 4 + q;
                    statS[row][wc * 2]     = rs[mt][q];
                    statS[row][wc * 2 + 1] = rq[mt][q];
                }
        }
        __syncthreads();                 // statS ready; pass-2 wlds reads done

        // stage Wl(lay+1) overlapped with LN epilogue
        if (lay == 0) {
            const unsigned short* mat = wbf + 16384;
            #pragma unroll
            for (int i = 0; i < 4; ++i) {
                int c = i * 512 + t;
                int col = c >> 4, kc = c & 15;
                uint4 v = *(const uint4*)(mat + col * 128 + kc * 8);
                *(uint4*)&wlds[col * 136 + kc * 8] = v;
            }
        }

        // normalize + relu -> y (bf16) -> hT  (no residual RMW)
        const float* lg = lng + (lay + 1) * 128;
        const float* lb = lnb + (lay + 1) * 128;
        float gam[4], bet[4];
        #pragma unroll
        for (int nt = 0; nt < 4; ++nt) {
            int col = wc * 64 + nt * 16 + lc;
            gam[nt] = lg[col]; bet[nt] = lb[col];
        }
        #pragma unroll
        for (int mt = 0; mt < 2; ++mt)
            #pragma unroll
            for (int q = 0; q < 4; ++q) {
                int row = wr * 32 + mt * 16 + li * 4 + q;
                float4 st = *(const float4*)&statS[row][0];
                float sum = st.x + st.z, sq = st.y + st.w;
                float mu   = sum * (1.f / 128.f);
                float var  = sq * (1.f / 128.f) - mu * mu;
                float rstd = rsqrtf(var + 1e-5f);
                #pragma unroll
                for (int nt = 0; nt < 4; ++nt) {
                    int col = wc * 64 + nt * 16 + lc;
                    float v = (acc[mt][nt][q] - mu) * rstd * gam[nt] + bet[nt];
                    hT[row][col] = f2bf(fmaxf(v, 0.f));
                }
            }
        __syncthreads();                 // hT(y) ready; Wl(lay+1) ready

        // residual: hA += yA (registers)
        #pragma unroll
        for (int mt = 0; mt < 2; ++mt)
            #pragma unroll
            for (int ks = 0; ks < 4; ++ks) {
                bf16x8 yA = *(const bf16x8*)&hT[wr * 32 + 16 * mt + lc][ks * 32 + kgrp];
                hA[mt][ks] = addbf(hA[mt][ks], yA);
            }
    }
    __syncthreads();                     // all yA reads done

    // dump final h (A-frag layout) -> hT
    if (wc == 0) {
        #pragma unroll
        for (int mt = 0; mt < 2; ++mt)
            #pragma unroll
            for (int ks = 0; ks < 4; ++ks)
                *(bf16x8*)&hT[wr * 32 + 16 * mt + lc][ks * 32 + kgrp] = hA[mt][ks];
    }
    __syncthreads();

    // ---- node mean -> patch features ----
    {
        const int gi = t >> 5, c0 = t & 31;
        #pragma unroll
        for (int k = 0; k < 4; ++k) {
            int c = c0 + 32 * k;
            float s = 0.f;
            #pragma unroll
            for (int j = 0; j < 8; ++j) s += bf2f(hT[gi * 8 + j][c]);
            pf[(size_t)(g0 + gi) * 128 + c] = s * 0.125f;
        }
    }
}

// =====================================================================
// K2: xg1 = pf(63488,128) @ wih1^T(384,128) + bih1 -> bf16.  MFMA, no LDS.
// =====================================================================
__global__ __launch_bounds__(256) void k2_xg(
    const float* __restrict__ src, const unsigned short* __restrict__ wB,
    const float* __restrict__ bias, unsigned short* __restrict__ out)
{
    const int t = threadIdx.x, w = t >> 6, l = t & 63;
    const int lc = l & 15, li = l >> 4;
    const int m0 = blockIdx.x * 64 + w * 16;

    bf16x8 aA[4];
    #pragma unroll
    for (int ks = 0; ks < 4; ++ks) {
        const float* p = src + (size_t)(m0 + lc) * 128 + ks * 32 + li * 8;
        float4 f0 = *(const float4*)p;
        float4 f1 = *(const float4*)(p + 4);
        bf16x8 v;
        v[0] = (short)f2bf(f0.x); v[1] = (short)f2bf(f0.y);
        v[2] = (short)f2bf(f0.z); v[3] = (short)f2bf(f0.w);
        v[4] = (short)f2bf(f1.x); v[5] = (short)f2bf(f1.y);
        v[6] = (short)f2bf(f1.z); v[7] = (short)f2bf(f1.w);
        aA[ks] = v;
    }
    #pragma unroll 2
    for (int nt = 0; nt < 24; ++nt) {
        f32x4 acc = (f32x4){0.f, 0.f, 0.f, 0.f};
        #pragma unroll
        for (int ks = 0; ks < 4; ++ks) {
            bf16x8 b = *(const bf16x8*)&wB[(size_t)(nt * 16 + lc) * 128 + ks * 32 + li * 8];
            acc = __builtin_amdgcn_mfma_f32_16x16x32_bf16(aA[ks], b, acc, 0, 0, 0);
        }
        float bv = bias[nt * 16 + lc];
        #pragma unroll
        for (int q = 0; q < 4; ++q) {
            int m = m0 + li * 4 + q;
            out[(size_t)m * 384 + nt * 16 + lc] = f2bf(acc[q] + bv);
        }
    }
}

// =====================================================================
// K3: both GRU layers fused, 31 steps in-kernel, weights in registers.
// =====================================================================
__global__ __launch_bounds__(512, 2) void k3_gru(
    const unsigned short* __restrict__ xg, const unsigned short* __restrict__ wbf,
    const float* __restrict__ bih, const float* __restrict__ bhh,
    float* __restrict__ gbuf)
{
    __shared__ unsigned short h1S[16][136];
    __shared__ unsigned short h2S[16][136];

    const int t = threadIdx.x, w = t >> 6, l = t & 63;
    const int lc = l & 15, li = l >> 4;
    const int col = w * 16 + lc;          // 0..127
    const int kgrp = li * 8;
    const int b0 = blockIdx.x * 8;
    const bool act = (li < 2);

    for (int i = t; i < 16 * 136; i += 512) {
        ((unsigned short*)h1S)[i] = 0;
        ((unsigned short*)h2S)[i] = 0;
    }

    const unsigned short* wih2 = wbf + 114688;
    const unsigned short* whh1 = wbf + 163840;
    const unsigned short* whh2 = wbf + 212992;
    bf16x8 Wh1[3][4], Wi2[3][4], Wh2[3][4];
    #pragma unroll
    for (int g = 0; g < 3; ++g)
        #pragma unroll
        for (int ks = 0; ks < 4; ++ks) {
            size_t off = (size_t)(g * 128 + col) * 128 + ks * 32 + kgrp;
            Wh1[g][ks] = *(const bf16x8*)(whh1 + off);
            Wi2[g][ks] = *(const bf16x8*)(wih2 + off);
            Wh2[g][ks] = *(const bf16x8*)(whh2 + off);
        }
    float bh1[3], bi2[3], bh2[3];
    #pragma unroll
    for (int g = 0; g < 3; ++g) {
        bh1[g] = bhh[g * 128 + col];
        bi2[g] = bih[384 + g * 128 + col];
        bh2[g] = bhh[384 + g * 128 + col];
    }

    float h1r[4] = {0.f, 0.f, 0.f, 0.f};
    float h2r[4] = {0.f, 0.f, 0.f, 0.f};
    float x1[3][4];

    if (act) {
        #pragma unroll
        for (int g = 0; g < 3; ++g)
            #pragma unroll
            for (int q = 0; q < 4; ++q)
                x1[g][q] = bf2f(xg[((size_t)(b0 + li * 4 + q) * 31 + 0) * 384 + g * 128 + col]);
    }
    __syncthreads();

    for (int ts = 0; ts < 31; ++ts) {
        bf16x8 aH[4];
        #pragma unroll
        for (int ks = 0; ks < 4; ++ks) aH[ks] = *(const bf16x8*)&h1S[lc][ks * 32 + kgrp];
        f32x4 acc[3];
        #pragma unroll
        for (int g = 0; g < 3; ++g) {
            acc[g] = (f32x4){0.f, 0.f, 0.f, 0.f};
            #pragma unroll
            for (int ks = 0; ks < 4; ++ks)
                acc[g] = __builtin_amdgcn_mfma_f32_16x16x32_bf16(aH[ks], Wh1[g][ks], acc[g], 0, 0, 0);
        }
        float xn[3][4];
        if (act && ts < 30) {
            #pragma unroll
            for (int g = 0; g < 3; ++g)
                #pragma unroll
                for (int q = 0; q < 4; ++q)
                    xn[g][q] = bf2f(xg[((size_t)(b0 + li * 4 + q) * 31 + ts + 1) * 384 + g * 128 + col]);
        }
        if (act) {
            #pragma unroll
            for (int q = 0; q < 4; ++q) {
                float r  = sigm(x1[0][q] + acc[0][q] + bh1[0]);
                float z  = sigm(x1[1][q] + acc[1][q] + bh1[1]);
                float nn = tanh_(x1[2][q] + r * (acc[2][q] + bh1[2]));
                h1r[q] = (1.f - z) * nn + z * h1r[q];
            }
        }
        __syncthreads();
        if (act) {
            #pragma unroll
            for (int q = 0; q < 4; ++q) h1S[li * 4 + q][col] = f2bf(h1r[q]);
        }
        __syncthreads();

        bf16x8 aH1n[4], aH2[4];
        #pragma unroll
        for (int ks = 0; ks < 4; ++ks) {
            aH1n[ks] = *(const bf16x8*)&h1S[lc][ks * 32 + kgrp];
            aH2[ks]  = *(const bf16x8*)&h2S[lc][ks * 32 + kgrp];
        }
        f32x4 ax2[3], ah2[3];
        #pragma unroll
        for (int g = 0; g < 3; ++g) {
            ax2[g] = (f32x4){0.f, 0.f, 0.f, 0.f};
            ah2[g] = (f32x4){0.f, 0.f, 0.f, 0.f};
            #pragma unroll
            for (int ks = 0; ks < 4; ++ks) {
                ax2[g] = __builtin_amdgcn_mfma_f32_16x16x32_bf16(aH1n[ks], Wi2[g][ks], ax2[g], 0, 0, 0);
                ah2[g] = __builtin_amdgcn_mfma_f32_16x16x32_bf16(aH2[ks],  Wh2[g][ks], ah2[g], 0, 0, 0);
            }
        }
        if (act) {
            #pragma unroll
            for (int q = 0; q < 4; ++q) {
                float xr = ax2[0][q] + bi2[0];
                float xz = ax2[1][q] + bi2[1];
                float xn2 = ax2[2][q] + bi2[2];
                float r  = sigm(xr + ah2[0][q] + bh2[0]);
                float z  = sigm(xz + ah2[1][q] + bh2[1]);
                float nn = tanh_(xn2 + r * (ah2[2][q] + bh2[2]));
                h2r[q] = (1.f - z) * nn + z * h2r[q];
            }
        }
        __syncthreads();
        if (act) {
            #pragma unroll
            for (int q = 0; q < 4; ++q) h2S[li * 4 + q][col] = f2bf(h2r[q]);
        }
        __syncthreads();

        #pragma unroll
        for (int g = 0; g < 3; ++g)
            #pragma unroll
            for (int q = 0; q < 4; ++q) x1[g][q] = xn[g][q];
    }

    if (act) {
        #pragma unroll
        for (int q = 0; q < 4; ++q)
            gbuf[(size_t)(b0 + li * 4 + q) * 128 + col] = h2r[q];
    }
}

// =====================================================================
// K4: logits = g(2048,128) @ etf(128,8)
// =====================================================================
__global__ __launch_bounds__(256) void k4_logits(
    const float* __restrict__ g, const float* __restrict__ etf, float* __restrict__ logits)
{
    const int idx = blockIdx.x * 256 + threadIdx.x;
    const int b = idx >> 3, c = idx & 7;
    float s = 0.f;
    #pragma unroll 8
    for (int f = 0; f < 128; ++f) s += g[(size_t)b * 128 + f] * etf[f * 8 + c];
    logits[idx] = s;
}

// =====================================================================
extern "C" void kernel_launch(void* const* d_in, const int* in_sizes, int n_in,
                              void* d_out, int out_size, void* d_ws, size_t ws_size,
                              hipStream_t stream) {
    const float* iq   = (const float*)d_in[0];
    const float* Wl0  = (const float*)d_in[1];
    const float* bl0  = (const float*)d_in[2];
    const float* Wr0  = (const float*)d_in[3];
    const float* Wl12 = (const float*)d_in[4];
    const float* bl12 = (const float*)d_in[5];
    const float* Wr12 = (const float*)d_in[6];
    const float* lng  = (const float*)d_in[7];
    const float* lnb  = (const float*)d_in[8];
    const float* wih  = (const float*)d_in[9];
    const float* whh  = (const float*)d_in[10];
    const float* bih  = (const float*)d_in[11];
    const float* bhh  = (const float*)d_in[12];
    const float* etf  = (const float*)d_in[13];

    float* out    = (float*)d_out;
    float* logits = out;                       // 2048*8
    float* gbuf   = out + 16384;               // 2048*128
    float* pf     = out + 16384 + 262144;      // 63488*128

    // ws: [wbf 262144 u16 = 512KB][xg1 bf16 63488*384 u16 = 48.76MB]
    unsigned short* wbf = (unsigned short*)d_ws;
    unsigned short* xg  = wbf + 262144;

    k0_wconv<<<1024, 256, 0, stream>>>(Wl12, Wr12, wih, whh, wbf);
    k1_sage<<<3968, 512, 0, stream>>>(iq, Wl0, bl0, Wr0, wbf, bl12, lng, lnb, pf);
    k2_xg<<<992, 256, 0, stream>>>(pf, wbf + 65536, bih, xg);
    k3_gru<<<256, 512, 0, stream>>>(xg, wbf, bih, bhh, gbuf);
    k4_logits<<<64, 256, 0, stream>>>(gbuf, etf, logits);
}